// Round 1
// baseline (1033.911 us; speedup 1.0000x reference)
//
#include <hip/hip_runtime.h>

#define D_ 512
#define ND_ 2048   // 4*D
#define KS_ 24
#define TB_ 32
#define B_ 8192

typedef __attribute__((ext_vector_type(8))) short short8;
typedef __attribute__((ext_vector_type(16))) float f32x16;
typedef unsigned short u16;

// byte offset into swizzled h tile: row in [0,32), kb = byte offset along d (d*2)
#define SWZ(row, kb) (((row) * 1024) + ((kb) ^ (((row) & 15) << 4)))

__device__ __forceinline__ u16 f2bf(float f) {
  union { float f; unsigned int u; } v; v.f = f;
  unsigned int u = v.u;
  return (u16)((u + 0x7FFFu + ((u >> 16) & 1u)) >> 16);
}

__device__ __forceinline__ float sigm(float x) { return 1.0f / (1.0f + __expf(-x)); }
__device__ __forceinline__ float tanh_(float x) {
  float e = __expf(2.0f * x);
  return (e - 1.0f) / (e + 1.0f);
}

// Pack Wu (512 x 2048 f32, row-major) into MFMA B-fragment order, bf16.
// Block (nt, ks): nt in [0,64) over 32-wide n-tiles, ks in [0,32) over K=16 slices.
// Within block: lane l, elem j  <->  B[k = ks*16 + 8*(l>>5) + j][n = nt*32 + (l&31)]
// Block storage: 64 lanes * 16B contiguous (1KB), block offset = (nt*32+ks)*1KB.
__global__ __launch_bounds__(256) void pack_wu_kernel(const float* __restrict__ Wu,
                                                      u16* __restrict__ pk) {
  int idx = blockIdx.x * 256 + threadIdx.x;  // 131072 total
  int lane = idx & 63;
  int blk  = idx >> 6;        // nt*32 + ks
  int ks   = blk & 31;
  int nt   = blk >> 5;
  int col  = nt * 32 + (lane & 31);
  int k0   = ks * 16 + (lane >> 5) * 8;
  u16 t[8];
#pragma unroll
  for (int j = 0; j < 8; ++j) t[j] = f2bf(Wu[(size_t)(k0 + j) * ND_ + col]);
  int4 w;
  w.x = t[0] | (t[1] << 16); w.y = t[2] | (t[3] << 16);
  w.z = t[4] | (t[5] << 16); w.w = t[6] | (t[7] << 16);
  *reinterpret_cast<int4*>(pk + (size_t)blk * 512 + lane * 8) = w;
}

template <int I>
__device__ __forceinline__ void chunk_step(
    unsigned char* hbuf, const float* x_lds, const u16* __restrict__ wu,
    const int (&rows)[16], const float (&wx)[4], const float (&bb)[4],
    float w1v, float w2v, int dc0, int l31, int lhi, int l,
    float (&creg)[16], float (&hreg)[16], float (&y1p)[16], float (&y2p)[16]) {
  const int dc = dc0 + I;
  f32x16 acc0 = {}, acc1 = {}, acc2 = {}, acc3 = {};
  const int abase = lhi * 16;
#pragma unroll 4
  for (int ks = 0; ks < 32; ++ks) {
    short8 a = *reinterpret_cast<const short8*>(&hbuf[SWZ(l31, ks * 32 + abase)]);
    const u16* bp = wu + (size_t)((dc * 32 + ks) * 512) + l * 8;
    short8 q0 = *reinterpret_cast<const short8*>(bp);
    short8 q1 = *reinterpret_cast<const short8*>(bp + 262144);   // gate f (+16*32*512)
    short8 q2 = *reinterpret_cast<const short8*>(bp + 524288);   // gate g
    short8 q3 = *reinterpret_cast<const short8*>(bp + 786432);   // gate o
    acc0 = __builtin_amdgcn_mfma_f32_32x32x16_bf16(a, q0, acc0, 0, 0, 0);
    acc1 = __builtin_amdgcn_mfma_f32_32x32x16_bf16(a, q1, acc1, 0, 0, 0);
    acc2 = __builtin_amdgcn_mfma_f32_32x32x16_bf16(a, q2, acc2, 0, 0, 0);
    acc3 = __builtin_amdgcn_mfma_f32_32x32x16_bf16(a, q3, acc3, 0, 0, 0);
  }
#pragma unroll
  for (int r = 0; r < 16; ++r) {
    float xv = x_lds[rows[r]];
    float zi = acc0[r] + xv * wx[0] + bb[0];
    float zf = acc1[r] + xv * wx[1] + bb[1];
    float zg = acc2[r] + xv * wx[2] + bb[2];
    float zo = acc3[r] + xv * wx[3] + bb[3];
    float ig = sigm(zi);
    float fg = sigm(zf);
    float gg = tanh_(zg);
    float og = sigm(zo);
    float cn = fg * creg[r] + ig * gg;
    creg[r] = cn;
    float hn = og * tanh_(cn);
    hreg[r] = hn;
    y1p[r] += hn * w1v;
    y2p[r] += hn * w2v;
  }
}

__global__ __launch_bounds__(512, 2) void lstm_kernel(
    const float* __restrict__ initial, const float* __restrict__ enc_h,
    const float* __restrict__ enc_c, const float* __restrict__ Wx,
    const float* __restrict__ bias, const float* __restrict__ w1,
    const float* __restrict__ b1, const float* __restrict__ w2,
    const float* __restrict__ b2, const u16* __restrict__ wu,
    float* __restrict__ out) {
  __shared__ __align__(16) unsigned char hbuf[TB_ * 1024];  // [32][512] bf16, swizzled
  __shared__ float x_lds[TB_];
  __shared__ float ly1[8][TB_];
  __shared__ float ly2[8][TB_];

  const int tid = threadIdx.x;
  const int wv  = tid >> 6;
  const int l   = tid & 63;
  const int l31 = l & 31;
  const int lhi = l >> 5;
  const int b0  = blockIdx.x * TB_;

  // ---- stage initial h into swizzled LDS (bf16) ----
  {
    int row = tid >> 4;   // 0..31
    int seg = tid & 15;   // 32 cols each
    const float* src = enc_h + (size_t)(b0 + row) * D_ + seg * 32;
#pragma unroll
    for (int jb = 0; jb < 4; ++jb) {
      u16 t[8];
#pragma unroll
      for (int j = 0; j < 8; ++j) t[j] = f2bf(src[jb * 8 + j]);
      int kb = seg * 64 + jb * 16;
      int4 w;
      w.x = t[0] | (t[1] << 16); w.y = t[2] | (t[3] << 16);
      w.z = t[4] | (t[5] << 16); w.w = t[6] | (t[7] << 16);
      *reinterpret_cast<int4*>(&hbuf[SWZ(row, kb)]) = w;
    }
  }
  if (tid < TB_) x_lds[tid] = initial[b0 + tid];

  // ---- per-lane step-invariant values ----
  const int dc0  = wv * 2;
  const int col0 = dc0 * 32 + l31;
  const int col1 = col0 + 32;
  float wxa[4], wxb[4], bba[4], bbb[4];
#pragma unroll
  for (int g = 0; g < 4; ++g) {
    wxa[g] = Wx[g * D_ + col0];
    wxb[g] = Wx[g * D_ + col1];
    bba[g] = bias[g * D_ + col0];
    bbb[g] = bias[g * D_ + col1];
  }
  const float w1a = w1[col0], w1b = w1[col1];
  const float w2a = w2[col0], w2b = w2[col1];
  const float b1v = b1[0], b2v = b2[0];

  int rows[16];
#pragma unroll
  for (int r = 0; r < 16; ++r) rows[r] = (r & 3) + 8 * (r >> 2) + 4 * lhi;

  float creg0[16], creg1[16];
#pragma unroll
  for (int r = 0; r < 16; ++r) {
    creg0[r] = enc_c[(size_t)(b0 + rows[r]) * D_ + col0];
    creg1[r] = enc_c[(size_t)(b0 + rows[r]) * D_ + col1];
  }

  __syncthreads();

  for (int s = 0; s < KS_; ++s) {
    float y1p[16], y2p[16];
#pragma unroll
    for (int r = 0; r < 16; ++r) { y1p[r] = 0.f; y2p[r] = 0.f; }
    float hreg0[16], hreg1[16];

    chunk_step<0>(hbuf, x_lds, wu, rows, wxa, bba, w1a, w2a, dc0, l31, lhi, l,
                  creg0, hreg0, y1p, y2p);
    chunk_step<1>(hbuf, x_lds, wu, rows, wxb, bbb, w1b, w2b, dc0, l31, lhi, l,
                  creg1, hreg1, y1p, y2p);

    // reduce y partials across the 32 d-columns held by this half-wave
#pragma unroll
    for (int m = 1; m < 32; m <<= 1) {
#pragma unroll
      for (int r = 0; r < 16; ++r) {
        y1p[r] += __shfl_xor(y1p[r], m);
        y2p[r] += __shfl_xor(y2p[r], m);
      }
    }
    if (l31 == 0) {
#pragma unroll
      for (int r = 0; r < 16; ++r) {
        ly1[wv][rows[r]] = y1p[r];
        ly2[wv][rows[r]] = y2p[r];
      }
    }
    __syncthreads();  // (1) all reads of hbuf done; ly slots written

    // overwrite hbuf with new h (single buffer, deferred from registers)
#pragma unroll
    for (int r = 0; r < 16; ++r) {
      *reinterpret_cast<u16*>(&hbuf[SWZ(rows[r], col0 * 2)]) = f2bf(hreg0[r]);
      *reinterpret_cast<u16*>(&hbuf[SWZ(rows[r], col1 * 2)]) = f2bf(hreg1[r]);
    }
    if (tid < TB_) {
      float s1 = b1v, s2 = b2v;
#pragma unroll
      for (int wq = 0; wq < 8; ++wq) { s1 += ly1[wq][tid]; s2 += ly2[wq][tid]; }
      float y1 = sigm(s1);
      float y2 = (s2 > 0.f) ? s2 : (__expf(s2) - 1.0f);
      out[(size_t)(b0 + tid) * KS_ + s] = y1;
      out[(size_t)B_ * KS_ + (size_t)(b0 + tid) * KS_ + s] = y2;
      x_lds[tid] = y1;
    }
    __syncthreads();  // (2) new h + x visible for next step
  }
}

extern "C" void kernel_launch(void* const* d_in, const int* in_sizes, int n_in,
                              void* d_out, int out_size, void* d_ws, size_t ws_size,
                              hipStream_t stream) {
  const float* initial = (const float*)d_in[0];
  const float* enc_h   = (const float*)d_in[1];
  const float* enc_c   = (const float*)d_in[2];
  const float* Wx      = (const float*)d_in[3];
  const float* Wu      = (const float*)d_in[4];
  const float* bias    = (const float*)d_in[5];
  const float* w1      = (const float*)d_in[6];
  const float* b1      = (const float*)d_in[7];
  const float* w2      = (const float*)d_in[8];
  const float* b2      = (const float*)d_in[9];
  u16* pk = (u16*)d_ws;  // 2 MB packed Wu (bf16, MFMA B-frag order)

  pack_wu_kernel<<<512, 256, 0, stream>>>(Wu, pk);
  lstm_kernel<<<256, 512, 0, stream>>>(initial, enc_h, enc_c, Wx, bias, w1, b1,
                                       w2, b2, pk, (float*)d_out);
}

// Round 2
// 955.598 us; speedup vs baseline: 1.0820x; 1.0820x over previous
//
#include <hip/hip_runtime.h>

#define D_ 512
#define ND_ 2048   // 4*D
#define KS_ 24
#define TB_ 32
#define B_ 8192

typedef __attribute__((ext_vector_type(8))) short short8;
typedef __attribute__((ext_vector_type(16))) float f32x16;
typedef unsigned short u16;

// byte offset into swizzled h tile: row in [0,32), kb = byte offset along d (d*2)
#define SWZ(row, kb) (((row) * 1024) + ((kb) ^ (((row) & 15) << 4)))

__device__ __forceinline__ u16 f2bf(float f) {
  union { float f; unsigned int u; } v; v.f = f;
  unsigned int u = v.u;
  return (u16)((u + 0x7FFFu + ((u >> 16) & 1u)) >> 16);
}

__device__ __forceinline__ float sigm(float x) { return 1.0f / (1.0f + __expf(-x)); }
__device__ __forceinline__ float tanh_(float x) {
  float e = __expf(2.0f * x);
  return (e - 1.0f) / (e + 1.0f);
}

// Pack Wu (512 x 2048 f32, row-major) into MFMA B-fragment order, bf16.
// Block (nt, ks): nt in [0,64) over 32-wide n-tiles, ks in [0,32) over K=16 slices.
// Within block: lane l, elem j  <->  B[k = ks*16 + 8*(l>>5) + j][n = nt*32 + (l&31)]
// Block storage: 64 lanes * 16B contiguous (1KB), block offset = (nt*32+ks)*1KB.
__global__ __launch_bounds__(256) void pack_wu_kernel(const float* __restrict__ Wu,
                                                      u16* __restrict__ pk) {
  int idx = blockIdx.x * 256 + threadIdx.x;  // 131072 total
  int lane = idx & 63;
  int blk  = idx >> 6;        // nt*32 + ks
  int ks   = blk & 31;
  int nt   = blk >> 5;
  int col  = nt * 32 + (lane & 31);
  int k0   = ks * 16 + (lane >> 5) * 8;
  u16 t[8];
#pragma unroll
  for (int j = 0; j < 8; ++j) t[j] = f2bf(Wu[(size_t)(k0 + j) * ND_ + col]);
  int4 w;
  w.x = t[0] | (t[1] << 16); w.y = t[2] | (t[3] << 16);
  w.z = t[4] | (t[5] << 16); w.w = t[6] | (t[7] << 16);
  *reinterpret_cast<int4*>(pk + (size_t)blk * 512 + lane * 8) = w;
}

// 256 blocks x 1024 threads (16 waves, 4 waves/SIMD). Wave wv owns d-cols
// [wv*32, wv*32+32) for all 4 gates; block owns 32 batch rows.
__global__ __launch_bounds__(1024, 4) void lstm_kernel(
    const float* __restrict__ initial, const float* __restrict__ enc_h,
    const float* __restrict__ enc_c, const float* __restrict__ Wx,
    const float* __restrict__ bias, const float* __restrict__ w1,
    const float* __restrict__ b1, const float* __restrict__ w2,
    const float* __restrict__ b2, const u16* __restrict__ wu,
    float* __restrict__ out) {
  __shared__ __align__(16) unsigned char hbuf[TB_ * 1024];  // [32][512] bf16, swizzled
  __shared__ float x_lds[TB_];
  __shared__ float ly1[16][TB_];
  __shared__ float ly2[16][TB_];

  const int tid = threadIdx.x;
  const int wv  = tid >> 6;    // 0..15  == dc (n-tile index within each gate region)
  const int l   = tid & 63;
  const int l31 = l & 31;
  const int lhi = l >> 5;
  const int b0  = blockIdx.x * TB_;

  // ---- stage initial h into swizzled LDS (bf16): 1024 threads, 16 cols each ----
  {
    int row = tid >> 5;   // 0..31
    int seg = tid & 31;   // 16 cols each
    const float* src = enc_h + (size_t)(b0 + row) * D_ + seg * 16;
#pragma unroll
    for (int jb = 0; jb < 2; ++jb) {
      u16 t[8];
#pragma unroll
      for (int j = 0; j < 8; ++j) t[j] = f2bf(src[jb * 8 + j]);
      int kb = seg * 32 + jb * 16;
      int4 w;
      w.x = t[0] | (t[1] << 16); w.y = t[2] | (t[3] << 16);
      w.z = t[4] | (t[5] << 16); w.w = t[6] | (t[7] << 16);
      *reinterpret_cast<int4*>(&hbuf[SWZ(row, kb)]) = w;
    }
  }
  if (tid < TB_) x_lds[tid] = initial[b0 + tid];

  // ---- per-lane step-invariant values ----
  const int col = wv * 32 + l31;     // d-column owned by this lane
  float wx[4], bb[4];
#pragma unroll
  for (int g = 0; g < 4; ++g) {
    wx[g] = Wx[g * D_ + col];
    bb[g] = bias[g * D_ + col];
  }
  const float w1v = w1[col], w2v = w2[col];
  const float b1v = b1[0], b2v = b2[0];

  int rows[16];
#pragma unroll
  for (int r = 0; r < 16; ++r) rows[r] = (r & 3) + 8 * (r >> 2) + 4 * lhi;

  float creg[16];
#pragma unroll
  for (int r = 0; r < 16; ++r)
    creg[r] = enc_c[(size_t)(b0 + rows[r]) * D_ + col];

  __syncthreads();

  const u16* wu_base = wu + (size_t)(wv * 32) * 512 + (size_t)l * 8;
  const int abase = lhi * 16;

  for (int s = 0; s < KS_; ++s) {
    f32x16 acc0 = {}, acc1 = {}, acc2 = {}, acc3 = {};
#pragma unroll 4
    for (int ks = 0; ks < 32; ++ks) {
      short8 a = *reinterpret_cast<const short8*>(&hbuf[SWZ(l31, ks * 32 + abase)]);
      const u16* bp = wu_base + (size_t)ks * 512;
      short8 q0 = *reinterpret_cast<const short8*>(bp);
      short8 q1 = *reinterpret_cast<const short8*>(bp + 262144);   // gate f
      short8 q2 = *reinterpret_cast<const short8*>(bp + 524288);   // gate g
      short8 q3 = *reinterpret_cast<const short8*>(bp + 786432);   // gate o
      acc0 = __builtin_amdgcn_mfma_f32_32x32x16_bf16(a, q0, acc0, 0, 0, 0);
      acc1 = __builtin_amdgcn_mfma_f32_32x32x16_bf16(a, q1, acc1, 0, 0, 0);
      acc2 = __builtin_amdgcn_mfma_f32_32x32x16_bf16(a, q2, acc2, 0, 0, 0);
      acc3 = __builtin_amdgcn_mfma_f32_32x32x16_bf16(a, q3, acc3, 0, 0, 0);
    }

    float y1p[16], y2p[16], hreg[16];
#pragma unroll
    for (int r = 0; r < 16; ++r) {
      float xv = x_lds[rows[r]];
      float zi = acc0[r] + xv * wx[0] + bb[0];
      float zf = acc1[r] + xv * wx[1] + bb[1];
      float zg = acc2[r] + xv * wx[2] + bb[2];
      float zo = acc3[r] + xv * wx[3] + bb[3];
      float ig = sigm(zi);
      float fg = sigm(zf);
      float gg = tanh_(zg);
      float og = sigm(zo);
      float cn = fg * creg[r] + ig * gg;
      creg[r] = cn;
      float hn = og * tanh_(cn);
      hreg[r] = hn;
      y1p[r] = hn * w1v;
      y2p[r] = hn * w2v;
    }

    // reduce y partials across the 32 d-columns held by this half-wave
#pragma unroll
    for (int m = 1; m < 32; m <<= 1) {
#pragma unroll
      for (int r = 0; r < 16; ++r) {
        y1p[r] += __shfl_xor(y1p[r], m);
        y2p[r] += __shfl_xor(y2p[r], m);
      }
    }
    if (l31 == 0) {
#pragma unroll
      for (int r = 0; r < 16; ++r) {
        ly1[wv][rows[r]] = y1p[r];
        ly2[wv][rows[r]] = y2p[r];
      }
    }
    __syncthreads();  // (1) all reads of hbuf done; ly slots written

    // overwrite hbuf with new h (single buffer, deferred from registers)
#pragma unroll
    for (int r = 0; r < 16; ++r)
      *reinterpret_cast<u16*>(&hbuf[SWZ(rows[r], col * 2)]) = f2bf(hreg[r]);

    if (tid < TB_) {
      float s1 = b1v, s2 = b2v;
#pragma unroll
      for (int wq = 0; wq < 16; ++wq) { s1 += ly1[wq][tid]; s2 += ly2[wq][tid]; }
      float y1 = sigm(s1);
      float y2 = (s2 > 0.f) ? s2 : (__expf(s2) - 1.0f);
      out[(size_t)(b0 + tid) * KS_ + s] = y1;
      out[(size_t)B_ * KS_ + (size_t)(b0 + tid) * KS_ + s] = y2;
      x_lds[tid] = y1;
    }
    __syncthreads();  // (2) new h + x visible for next step
  }
}

extern "C" void kernel_launch(void* const* d_in, const int* in_sizes, int n_in,
                              void* d_out, int out_size, void* d_ws, size_t ws_size,
                              hipStream_t stream) {
  const float* initial = (const float*)d_in[0];
  const float* enc_h   = (const float*)d_in[1];
  const float* enc_c   = (const float*)d_in[2];
  const float* Wx      = (const float*)d_in[3];
  const float* Wu      = (const float*)d_in[4];
  const float* bias    = (const float*)d_in[5];
  const float* w1      = (const float*)d_in[6];
  const float* b1      = (const float*)d_in[7];
  const float* w2      = (const float*)d_in[8];
  const float* b2      = (const float*)d_in[9];
  u16* pk = (u16*)d_ws;  // 2 MB packed Wu (bf16, MFMA B-frag order)

  pack_wu_kernel<<<512, 256, 0, stream>>>(Wu, pk);
  lstm_kernel<<<256, 1024, 0, stream>>>(initial, enc_h, enc_c, Wx, bias, w1, b1,
                                        w2, b2, pk, (float*)d_out);
}